// Round 4
// baseline (2360.814 us; speedup 1.0000x reference)
//
#include <hip/hip_runtime.h>

#define HID     128
#define DINK    272      // 2*HID + 16
#define BE      32       // edges per block
#define MSG_LD  276      // 272 + 4 pad (keeps float4 alignment, offsets banks)
#define Z1_LD   132      // 128 + 4 pad

__device__ __forceinline__ float fast_silu(float v) {
    return __fdividef(v, 1.0f + __expf(-v));
}

// One block: 32 edges. Phases: gather msg tile -> GEMM1(272x128) -> silu ->
// GEMM2(128x128) -> silu -> dot W3 -> tanh -> atomic scatter into agg.
__global__ __launch_bounds__(256) void edge_mlp_kernel(
    const float* __restrict__ h,
    const int* __restrict__ eidx,        // harness delivers int64 inputs as int32: [2, E]
    const float* __restrict__ edge_attr,
    const float* __restrict__ coord_diff,
    const float* __restrict__ W1,
    const float* __restrict__ b1,
    const float* __restrict__ W2,
    const float* __restrict__ b2,
    const float* __restrict__ W3,
    float* __restrict__ agg,
    int E)
{
    __shared__ float s_msg[BE][MSG_LD];
    __shared__ float s_z1[BE][Z1_LD];
    __shared__ int   s_row[BE];

    const int t  = threadIdx.x;
    const int be = blockIdx.x * BE;

    // ---------- gather: 8 threads per edge, float4 chunks ----------
    {
        const int el = t >> 3;       // 0..31 local edge
        const int s  = t & 7;
        const int e  = be + el;
        const int ec = (e < E) ? e : 0;
        const int row = eidx[ec];            // edge_index[0][e]
        const int col = eidx[(size_t)E + ec];// edge_index[1][e]
        if (s == 0) s_row[el] = row;
        const float4* hr = (const float4*)(h + (size_t)row * HID);
        const float4* hc = (const float4*)(h + (size_t)col * HID);
        const float4* ea = (const float4*)(edge_attr + (size_t)ec * 16);
        #pragma unroll
        for (int i = 0; i < 9; ++i) {
            const int q = s + 8 * i;   // float4 chunk id, 0..67
            if (q < 68) {
                float4 v;
                if (q < 32)      v = hr[q];
                else if (q < 64) v = hc[q - 32];
                else             v = ea[q - 64];
                *(float4*)&s_msg[el][q * 4] = v;
            }
        }
    }
    __syncthreads();

    const int jt = t & 15;           // 16 threads across the 128 outputs
    const int et = t >> 4;           // 16 thread-groups across edges
    const int j0 = jt * 8;
    const int e0 = et * 2;

    // ---------- GEMM1: z1 = silu(msg @ W1 + b1) ----------
    float acc[2][8];
    #pragma unroll
    for (int jj = 0; jj < 8; ++jj) {
        const float bv = b1[j0 + jj];
        acc[0][jj] = bv;
        acc[1][jj] = bv;
    }
    {
        const float4* Wv = (const float4*)W1;
        #pragma unroll 4
        for (int k = 0; k < DINK; ++k) {
            const float a0 = s_msg[e0][k];
            const float a1 = s_msg[e0 + 1][k];
            const float4 w0 = Wv[k * (HID / 4) + (j0 >> 2)];
            const float4 w1 = Wv[k * (HID / 4) + (j0 >> 2) + 1];
            const float w[8] = {w0.x, w0.y, w0.z, w0.w, w1.x, w1.y, w1.z, w1.w};
            #pragma unroll
            for (int jj = 0; jj < 8; ++jj) {
                acc[0][jj] = fmaf(a0, w[jj], acc[0][jj]);
                acc[1][jj] = fmaf(a1, w[jj], acc[1][jj]);
            }
        }
    }
    #pragma unroll
    for (int i = 0; i < 2; ++i) {
        float4 v0, v1;
        v0.x = fast_silu(acc[i][0]); v0.y = fast_silu(acc[i][1]);
        v0.z = fast_silu(acc[i][2]); v0.w = fast_silu(acc[i][3]);
        v1.x = fast_silu(acc[i][4]); v1.y = fast_silu(acc[i][5]);
        v1.z = fast_silu(acc[i][6]); v1.w = fast_silu(acc[i][7]);
        *(float4*)&s_z1[e0 + i][j0]     = v0;
        *(float4*)&s_z1[e0 + i][j0 + 4] = v1;
    }
    __syncthreads();

    // ---------- GEMM2: z2 = silu(z1 @ W2 + b2) ----------
    #pragma unroll
    for (int jj = 0; jj < 8; ++jj) {
        const float bv = b2[j0 + jj];
        acc[0][jj] = bv;
        acc[1][jj] = bv;
    }
    {
        const float4* Wv = (const float4*)W2;
        #pragma unroll 4
        for (int k = 0; k < HID; ++k) {
            const float a0 = s_z1[e0][k];
            const float a1 = s_z1[e0 + 1][k];
            const float4 w0 = Wv[k * (HID / 4) + (j0 >> 2)];
            const float4 w1 = Wv[k * (HID / 4) + (j0 >> 2) + 1];
            const float w[8] = {w0.x, w0.y, w0.z, w0.w, w1.x, w1.y, w1.z, w1.w};
            #pragma unroll
            for (int jj = 0; jj < 8; ++jj) {
                acc[0][jj] = fmaf(a0, w[jj], acc[0][jj]);
                acc[1][jj] = fmaf(a1, w[jj], acc[1][jj]);
            }
        }
    }

    // ---------- scale = tanh(z2 @ W3): partial dot + 16-lane reduce ----------
    float p0 = 0.0f, p1 = 0.0f;
    #pragma unroll
    for (int jj = 0; jj < 8; ++jj) {
        const float w3 = W3[j0 + jj];
        p0 = fmaf(fast_silu(acc[0][jj]), w3, p0);
        p1 = fmaf(fast_silu(acc[1][jj]), w3, p1);
    }
    #pragma unroll
    for (int m = 1; m < 16; m <<= 1) {
        p0 += __shfl_xor(p0, m, 64);
        p1 += __shfl_xor(p1, m, 64);
    }

    if (jt == 0) {
        #pragma unroll
        for (int i = 0; i < 2; ++i) {
            const int e = be + e0 + i;
            if (e < E) {
                // tanhf (not exp-based): W3 gain is 0.001 so the argument is
                // ~1e-2; (e^2v-1)/(e^2v+1) would cancel catastrophically there.
                const float sc = tanhf(i == 0 ? p0 : p1) * 15.0f;  // COORDS_RANGE
                const int row = s_row[e0 + i];
                const float* cd = coord_diff + (size_t)e * 3;
                atomicAdd(&agg[row * 3 + 0], cd[0] * sc);
                atomicAdd(&agg[row * 3 + 1], cd[1] * sc);
                atomicAdd(&agg[row * 3 + 2], cd[2] * sc);
            }
        }
    }
}

__global__ void finalize_kernel(const float* __restrict__ x,
                                const float* __restrict__ flags,
                                float* __restrict__ out, int n3)
{
    const int i = blockIdx.x * blockDim.x + threadIdx.x;
    if (i < n3) {
        const int n = i / 3;
        out[i] = (out[i] + x[i]) * flags[n];
    }
}

extern "C" void kernel_launch(void* const* d_in, const int* in_sizes, int n_in,
                              void* d_out, int out_size, void* d_ws, size_t ws_size,
                              hipStream_t stream)
{
    const float* h          = (const float*)d_in[0];
    const float* x          = (const float*)d_in[1];
    const int*   eix        = (const int*)d_in[2];   // int64 in reference -> int32 here
    const float* edge_attr  = (const float*)d_in[3];
    const float* coord_diff = (const float*)d_in[4];
    const float* flags      = (const float*)d_in[5];
    // d_in[6] = edge_mask: computed-but-unused in the reference; faithfully ignored.
    const float* W1 = (const float*)d_in[7];
    const float* b1 = (const float*)d_in[8];
    const float* W2 = (const float*)d_in[9];
    const float* b2 = (const float*)d_in[10];
    const float* W3 = (const float*)d_in[11];
    float* out = (float*)d_out;

    const int N3 = in_sizes[1];          // N_NODES * 3
    const int E  = in_sizes[4] / 3;      // from coord_diff

    // d_out doubles as the aggregation buffer: zero it, scatter-add, finalize in place.
    hipMemsetAsync(out, 0, (size_t)N3 * sizeof(float), stream);

    const int nblk = (E + BE - 1) / BE;
    edge_mlp_kernel<<<nblk, 256, 0, stream>>>(h, eix, edge_attr, coord_diff,
                                              W1, b1, W2, b2, W3, out, E);
    finalize_kernel<<<(N3 + 255) / 256, 256, 0, stream>>>(x, flags, out, N3);
}

// Round 5
// 329.622 us; speedup vs baseline: 7.1622x; 7.1622x over previous
//
#include <hip/hip_runtime.h>

typedef short  short8   __attribute__((ext_vector_type(8)));
typedef float  floatx16 __attribute__((ext_vector_type(16)));

#define HID  128
#define LDM  296   // msg row stride in bf16 elems (16B-aligned rows, 2-way-max banks)
#define LDZ  136   // z1 row stride
#define NK1  18    // K-steps GEMM1: 288/16 (272 zero-padded to 288)
#define NK2  8     // K-steps GEMM2: 128/16

__device__ __forceinline__ float fast_silu(float v) {
    return __fdividef(v, 1.0f + __expf(-v));
}
// f32 -> bf16 round-to-nearest-even
__device__ __forceinline__ unsigned short f2bf(float f) {
    union { float f; unsigned int u; } v; v.f = f;
    unsigned int r = v.u + 0x7FFFu + ((v.u >> 16) & 1u);
    return (unsigned short)(r >> 16);
}

// ---- prep A: W1 [272][128] -> W1T fragment-linear bf16 (K padded to 288); W2 likewise ----
// fragment-linear: chunk index ((tn*NKS + ks)*64 + lane), 8 bf16 per chunk;
// lane supplies rows n = 32*tn + (lane&31), k = 16*ks + 8*(lane>>5) + j.
__global__ void prep_weights(const float* __restrict__ W1, const float* __restrict__ W2,
                             unsigned short* __restrict__ w1t, unsigned short* __restrict__ w2t)
{
    const int tid = blockIdx.x * 256 + threadIdx.x;
    if (tid < 4 * NK1 * 64) {
        const int tn   = tid / (NK1 * 64);
        const int rem  = tid % (NK1 * 64);
        const int ks   = rem / 64;
        const int lane = rem % 64;
        const int n  = 32 * tn + (lane & 31);
        const int kb = 16 * ks + 8 * (lane >> 5);
        unsigned short o[8];
        #pragma unroll
        for (int j = 0; j < 8; ++j) {
            const int k = kb + j;
            o[j] = (k < 272) ? f2bf(W1[(size_t)k * HID + n]) : (unsigned short)0;
        }
        #pragma unroll
        for (int j = 0; j < 8; ++j) w1t[(size_t)tid * 8 + j] = o[j];
    } else if (tid < 4 * NK1 * 64 + 4 * NK2 * 64) {
        const int id   = tid - 4 * NK1 * 64;
        const int tn   = id / (NK2 * 64);
        const int rem  = id % (NK2 * 64);
        const int ks   = rem / 64;
        const int lane = rem % 64;
        const int n  = 32 * tn + (lane & 31);
        const int kb = 16 * ks + 8 * (lane >> 5);
        #pragma unroll
        for (int j = 0; j < 8; ++j)
            w2t[(size_t)id * 8 + j] = f2bf(W2[(size_t)(kb + j) * HID + n]);
    }
}

// ---- prep B: cast h and edge_attr to bf16 ----
__global__ void prep_cast(const float* __restrict__ h, const float* __restrict__ ea,
                          unsigned short* __restrict__ hb, unsigned short* __restrict__ eab,
                          int nh, int nea)
{
    const int total4 = (nh + nea) >> 2;
    for (int i = blockIdx.x * blockDim.x + threadIdx.x; i < total4; i += gridDim.x * blockDim.x) {
        float4 v;
        unsigned short* dst;
        if (i < (nh >> 2)) { v = ((const float4*)h)[i];            dst = hb  + (size_t)i * 4; }
        else               { v = ((const float4*)ea)[i - (nh>>2)]; dst = eab + (size_t)(i - (nh>>2)) * 4; }
        const unsigned int lo = (unsigned int)f2bf(v.x) | ((unsigned int)f2bf(v.y) << 16);
        const unsigned int hi = (unsigned int)f2bf(v.z) | ((unsigned int)f2bf(v.w) << 16);
        *(uint2*)dst = make_uint2(lo, hi);
    }
}

// ---- main: persistent blocks, 64 edges/iter, 4 waves, 32x32x16 bf16 MFMA ----
__global__ __launch_bounds__(256, 2) void egnn_mfma_kernel(
    const unsigned short* __restrict__ hb,    // [N][128] bf16
    const int* __restrict__ eidx,             // [2][E]
    const unsigned short* __restrict__ eab,   // [E][16] bf16
    const float* __restrict__ coord_diff,     // [E][3]
    const unsigned short* __restrict__ w1t,   // fragment-linear
    const unsigned short* __restrict__ w2t,
    const float* __restrict__ b1,
    const float* __restrict__ b2,
    const float* __restrict__ W3,
    float* __restrict__ agg,
    int E, int niter)
{
    __shared__ unsigned short s_msg[64][LDM];  // 37,888 B
    __shared__ unsigned short s_z1[64][LDZ];   // 17,408 B
    __shared__ float s_z3[64];
    __shared__ int   s_row[64];

    const int t    = threadIdx.x;
    const int lane = t & 63;
    const int w    = t >> 6;        // wave id = n-tile
    const int c31  = lane & 31;
    const int hi   = lane >> 5;

    // per-wave bias/W3 fragments: n = 32w + (r&3) + 8*(r>>2) + 4*hi  (C/D row map)
    float b1f[16], b2f[16], w3f[16];
    #pragma unroll
    for (int r = 0; r < 16; ++r) {
        const int n = 32 * w + (r & 3) + 8 * (r >> 2) + 4 * hi;
        b1f[r] = b1[n]; b2f[r] = b2[n]; w3f[r] = W3[n];
    }

    for (int it = blockIdx.x; it < niter; it += gridDim.x) {
        const int ebase = it * 64;

        // ---------- gather: 4 threads per edge ----------
        {
            const int e = t >> 2, s = t & 3;
            const int g  = ebase + e;
            const int gc = (g < E) ? g : (E - 1);
            const int row = eidx[gc];
            const int col = eidx[(size_t)E + gc];
            if (s == 0) s_row[e] = row;
            if (t < 64) s_z3[t] = 0.0f;
            const uint4* hr = (const uint4*)(hb + (size_t)row * HID);
            const uint4* hc = (const uint4*)(hb + (size_t)col * HID);
            #pragma unroll
            for (int i = 0; i < 4; ++i) {
                const int q = s + 4 * i;             // 0..15 (16B chunks of 8 bf16)
                *(uint4*)&s_msg[e][q * 8]       = hr[q];
                *(uint4*)&s_msg[e][HID + q * 8] = hc[q];
            }
            const uint4* ea4 = (const uint4*)(eab + (size_t)gc * 16);
            if (s < 2) *(uint4*)&s_msg[e][256 + s * 8] = ea4[s];
            else       *(uint4*)&s_msg[e][256 + s * 8] = make_uint4(0u, 0u, 0u, 0u); // k 272..287 = 0
        }
        __syncthreads();

        // ---------- GEMM1: z1 = silu(msg @ W1 + b1), computed as D[n][e] ----------
        floatx16 acc0 = {}, acc1 = {};
        #pragma unroll
        for (int ks = 0; ks < NK1; ++ks) {
            const short8 wf = *(const short8*)(w1t + ((size_t)(w * NK1 + ks) * 64 + lane) * 8);
            const short8 a0 = *(const short8*)&s_msg[c31][16 * ks + 8 * hi];
            const short8 a1 = *(const short8*)&s_msg[32 + c31][16 * ks + 8 * hi];
            acc0 = __builtin_amdgcn_mfma_f32_32x32x16_bf16(wf, a0, acc0, 0, 0, 0);
            acc1 = __builtin_amdgcn_mfma_f32_32x32x16_bf16(wf, a1, acc1, 0, 0, 0);
        }
        // bias + silu + pack to z1 LDS [e][n1]
        #pragma unroll
        for (int te = 0; te < 2; ++te) {
            const floatx16& A = te ? acc1 : acc0;
            const int e = 32 * te + c31;
            #pragma unroll
            for (int q = 0; q < 4; ++q) {
                const float f0 = fast_silu(A[4*q+0] + b1f[4*q+0]);
                const float f1 = fast_silu(A[4*q+1] + b1f[4*q+1]);
                const float f2 = fast_silu(A[4*q+2] + b1f[4*q+2]);
                const float f3 = fast_silu(A[4*q+3] + b1f[4*q+3]);
                const unsigned int lo = (unsigned int)f2bf(f0) | ((unsigned int)f2bf(f1) << 16);
                const unsigned int hw = (unsigned int)f2bf(f2) | ((unsigned int)f2bf(f3) << 16);
                *(uint2*)&s_z1[e][32 * w + 8 * q + 4 * hi] = make_uint2(lo, hw);
            }
        }
        __syncthreads();

        // ---------- GEMM2: z2 = silu(z1 @ W2 + b2) -> dot W3 ----------
        floatx16 g0 = {}, g1 = {};
        #pragma unroll
        for (int ks = 0; ks < NK2; ++ks) {
            const short8 wf = *(const short8*)(w2t + ((size_t)(w * NK2 + ks) * 64 + lane) * 8);
            const short8 a0 = *(const short8*)&s_z1[c31][16 * ks + 8 * hi];
            const short8 a1 = *(const short8*)&s_z1[32 + c31][16 * ks + 8 * hi];
            g0 = __builtin_amdgcn_mfma_f32_32x32x16_bf16(wf, a0, g0, 0, 0, 0);
            g1 = __builtin_amdgcn_mfma_f32_32x32x16_bf16(wf, a1, g1, 0, 0, 0);
        }
        float p0 = 0.0f, p1 = 0.0f;
        #pragma unroll
        for (int r = 0; r < 16; ++r) {
            p0 += fast_silu(g0[r] + b2f[r]) * w3f[r];
            p1 += fast_silu(g1[r] + b2f[r]) * w3f[r];
        }
        p0 += __shfl_xor(p0, 32, 64);
        p1 += __shfl_xor(p1, 32, 64);
        if (hi == 0) {
            atomicAdd(&s_z3[c31], p0);
            atomicAdd(&s_z3[32 + c31], p1);
        }
        __syncthreads();

        // ---------- epilogue: tanh, scale, scatter ----------
        if (t < 64) {
            const int g = ebase + t;
            if (g < E) {
                const float sc = tanhf(s_z3[t]) * 15.0f;   // COORDS_RANGE
                const int row = s_row[t];
                const float* cd = coord_diff + (size_t)g * 3;
                atomicAdd(&agg[row * 3 + 0], cd[0] * sc);
                atomicAdd(&agg[row * 3 + 1], cd[1] * sc);
                atomicAdd(&agg[row * 3 + 2], cd[2] * sc);
            }
        }
        __syncthreads();   // protect s_msg/s_row/s_z3 before next iter
    }
}

__global__ void finalize_kernel(const float* __restrict__ x,
                                const float* __restrict__ flags,
                                float* __restrict__ out, int n3)
{
    const int i = blockIdx.x * blockDim.x + threadIdx.x;
    if (i < n3) {
        const int n = i / 3;
        out[i] = (out[i] + x[i]) * flags[n];
    }
}

extern "C" void kernel_launch(void* const* d_in, const int* in_sizes, int n_in,
                              void* d_out, int out_size, void* d_ws, size_t ws_size,
                              hipStream_t stream)
{
    const float* h          = (const float*)d_in[0];
    const float* x          = (const float*)d_in[1];
    const int*   eix        = (const int*)d_in[2];
    const float* edge_attr  = (const float*)d_in[3];
    const float* coord_diff = (const float*)d_in[4];
    const float* flags      = (const float*)d_in[5];
    // d_in[6] edge_mask: computed-but-unused in reference; ignored.
    const float* W1 = (const float*)d_in[7];
    const float* b1 = (const float*)d_in[8];
    const float* W2 = (const float*)d_in[9];
    const float* b2 = (const float*)d_in[10];
    const float* W3 = (const float*)d_in[11];
    float* out = (float*)d_out;

    const int N3 = in_sizes[1];       // N_NODES * 3
    const int E  = in_sizes[4] / 3;
    const int nh  = in_sizes[0];      // N_NODES * 128
    const int nea = in_sizes[3];      // E * 16

    // d_ws layout (bytes): [0, 73728) W1T | [73728, 106496) W2T | h_bf16 | ea_bf16
    unsigned short* w1t = (unsigned short*)d_ws;
    unsigned short* w2t = w1t + 4 * NK1 * 64 * 8;                   // short offset 36864
    unsigned short* hb  = (unsigned short*)((char*)d_ws + 106496);
    unsigned short* eab = hb + (size_t)nh;

    hipMemsetAsync(out, 0, (size_t)N3 * sizeof(float), stream);
    prep_weights<<<26, 256, 0, stream>>>(W1, W2, w1t, w2t);
    prep_cast<<<2048, 256, 0, stream>>>(h, edge_attr, hb, eab, nh, nea);

    const int niter = (E + 63) / 64;
    egnn_mfma_kernel<<<512, 256, 0, stream>>>(hb, eix, eab, coord_diff,
                                              w1t, w2t, b1, b2, W3, out, E, niter);
    finalize_kernel<<<(N3 + 255) / 256, 256, 0, stream>>>(x, flags, out, N3);
}